// Round 5
// baseline (638.347 us; speedup 1.0000x reference)
//
#include <hip/hip_runtime.h>
#include <math.h>

#define B 8
#define S 1024
#define D 768
#define H 12
#define V 50257
#define DFF 3072
#define HD (H*D)      // 9216
#define SLO 1012      // first s needed (head 11, last 12 positions of y feed x row 1023)
#define NS 12

// workspace layout (float offsets)
#define OFF_EMEAN 0                     // 768   (atomic sum; divide by V on read)
#define OFF_A     768                   // B*NS*D = 73728 (atomic)
#define OFF_SC    (OFF_A + B*NS*D)      // NS*S = 12288 (scores -> attn in place)
#define OFF_YV    (OFF_SC + NS*S)       // B*HD = 73728
#define OFF_YO    (OFF_YV + B*HD)       // B*D = 6144
#define OFF_G     (OFF_YO + B*D)        // B*DFF = 24576
#define OFF_X     (OFF_G + B*DFF)       // B*D = 6144 (atomic; zeroed by memset2)

// ---- multi-value butterfly reductions ----------------------------------
__device__ __forceinline__ float fold8(const float acc[8], int lane) {
    float x[4];
#pragma unroll
    for (int i = 0; i < 4; ++i) {
        bool s = lane & 1;
        float a = s ? acc[2*i+1] : acc[2*i];
        float b = s ? acc[2*i]   : acc[2*i+1];
        x[i] = a + __shfl_xor(b, 1, 64);
    }
    float y[2];
#pragma unroll
    for (int i = 0; i < 2; ++i) {
        bool s = lane & 2;
        float a = s ? x[2*i+1] : x[2*i];
        float b = s ? x[2*i]   : x[2*i+1];
        y[i] = a + __shfl_xor(b, 2, 64);
    }
    bool s = lane & 4;
    float a = s ? y[1] : y[0];
    float b = s ? y[0] : y[1];
    float z = a + __shfl_xor(b, 4, 64);
    z += __shfl_xor(z, 8, 64);
    z += __shfl_xor(z, 16, 64);
    z += __shfl_xor(z, 32, 64);
    return z;
}

__device__ __forceinline__ float fold16(const float acc[16], int lane) {
    float x[8];
#pragma unroll
    for (int i = 0; i < 8; ++i) {
        bool s = lane & 1;
        float a = s ? acc[2*i+1] : acc[2*i];
        float b = s ? acc[2*i]   : acc[2*i+1];
        x[i] = a + __shfl_xor(b, 1, 64);
    }
    float y[4];
#pragma unroll
    for (int i = 0; i < 4; ++i) {
        bool s = lane & 2;
        float a = s ? x[2*i+1] : x[2*i];
        float b = s ? x[2*i]   : x[2*i+1];
        y[i] = a + __shfl_xor(b, 2, 64);
    }
    float z2[2];
#pragma unroll
    for (int i = 0; i < 2; ++i) {
        bool s = lane & 4;
        float a = s ? y[2*i+1] : y[2*i];
        float b = s ? y[2*i]   : y[2*i+1];
        z2[i] = a + __shfl_xor(b, 4, 64);
    }
    bool s = lane & 8;
    float a = s ? z2[1] : z2[0];
    float b = s ? z2[0] : z2[1];
    float z = a + __shfl_xor(b, 8, 64);
    z += __shfl_xor(z, 16, 64);
    z += __shfl_xor(z, 32, 64);
    return z;
}

// ---- K1: column sums of wte. Flat grid-stride, TLP-saturated.
// block=192, grid=2560 -> 10 blocks/CU = 30 waves/CU (VGPR ~30, no cap).
// Total threads NT = 491520 is a multiple of 192, so every grid-stride
// element of a thread has the same float4-column (= threadIdx.x).
#define K1_G 2560
__global__ __launch_bounds__(192) void k1_emean(const float* __restrict__ wte,
                                                float* __restrict__ ws) {
    const float4* __restrict__ wte4 = reinterpret_cast<const float4*>(wte);
    const size_t NT = (size_t)K1_G * 192;                 // 491520
    const size_t N4 = (size_t)V * 192;                    // 9649344
    size_t i = (size_t)blockIdx.x * 192 + threadIdx.x;
    float4 a0 = {0,0,0,0}, a1 = {0,0,0,0}, a2 = {0,0,0,0}, a3 = {0,0,0,0};
    for (; i + 3 * NT < N4; i += 4 * NT) {
        float4 t0 = wte4[i];
        float4 t1 = wte4[i + NT];
        float4 t2 = wte4[i + 2 * NT];
        float4 t3 = wte4[i + 3 * NT];
        a0.x += t0.x; a0.y += t0.y; a0.z += t0.z; a0.w += t0.w;
        a1.x += t1.x; a1.y += t1.y; a1.z += t1.z; a1.w += t1.w;
        a2.x += t2.x; a2.y += t2.y; a2.z += t2.z; a2.w += t2.w;
        a3.x += t3.x; a3.y += t3.y; a3.z += t3.z; a3.w += t3.w;
    }
    for (; i < N4; i += NT) {
        float4 t = wte4[i];
        a0.x += t.x; a0.y += t.y; a0.z += t.z; a0.w += t.w;
    }
    a0.x += a1.x + a2.x + a3.x;
    a0.y += a1.y + a2.y + a3.y;
    a0.z += a1.z + a2.z + a3.z;
    a0.w += a1.w + a2.w + a3.w;
    const int c = threadIdx.x;
    atomicAdd(&ws[OFF_EMEAN + 4 * c + 0], a0.x);
    atomicAdd(&ws[OFF_EMEAN + 4 * c + 1], a0.y);
    atomicAdd(&ws[OFF_EMEAN + 4 * c + 2], a0.z);
    atomicAdd(&ws[OFF_EMEAN + 4 * c + 3], a0.w);
}

// ---- K2: scores[s12,t] = sum_d wpe[t,d]*wpe[s+1,d]*wq[11,d]*wk[11,d].
// wave per t. grid 256 x 256
__global__ __launch_bounds__(256) void k2_scores(const float* __restrict__ wpe,
                                                 const float* __restrict__ wq,
                                                 const float* __restrict__ wk,
                                                 float* __restrict__ ws) {
    const float4* __restrict__ wpe4 = reinterpret_cast<const float4*>(wpe);
    const int lane = threadIdx.x & 63;
    const int t = (blockIdx.x * 256 + threadIdx.x) >> 6;      // 0..1023
    float4 p[3], qk[3];
#pragma unroll
    for (int i = 0; i < 3; ++i) {
        p[i] = wpe4[(size_t)t * 192 + lane + 64 * i];
        float4 q = *reinterpret_cast<const float4*>(wq + 11 * D + 4 * lane + 256 * i);
        float4 k = *reinterpret_cast<const float4*>(wk + 11 * D + 4 * lane + 256 * i);
        qk[i].x = p[i].x * q.x * k.x;
        qk[i].y = p[i].y * q.y * k.y;
        qk[i].z = p[i].z * q.z * k.z;
        qk[i].w = p[i].w * q.w * k.w;
    }
    float acc[16];
#pragma unroll
    for (int s12 = 0; s12 < 12; ++s12) {
        float a = 0.f;
#pragma unroll
        for (int i = 0; i < 3; ++i) {
            float4 pe = wpe4[(size_t)(SLO + s12 + 1) * 192 + lane + 64 * i];
            a += pe.x * qk[i].x + pe.y * qk[i].y + pe.z * qk[i].z + pe.w * qk[i].w;
        }
        acc[s12] = a;
    }
    acc[12] = acc[13] = acc[14] = acc[15] = 0.f;
    float z = fold16(acc, lane);
    if (lane < 12) ws[OFF_SC + lane * S + t] = z;
}

// ---- K3: softmax rows (masked t<=s), writes attn in place. grid 12 x 256
__global__ __launch_bounds__(256) void k3_softmax(float* __restrict__ ws) {
    __shared__ float red[256];
    const int s12 = blockIdx.x, tid = threadIdx.x;
    const int n = SLO + s12 + 1;
    float* sc = ws + OFF_SC + s12 * S;
    float m = -1e30f;
#pragma unroll
    for (int k = 0; k < 4; ++k) { int t = tid + 256 * k; if (t < n) m = fmaxf(m, sc[t]); }
    red[tid] = m; __syncthreads();
    for (int off = 128; off; off >>= 1) { if (tid < off) red[tid] = fmaxf(red[tid], red[tid + off]); __syncthreads(); }
    float mx = red[0]; __syncthreads();
    float sum = 0.f;
#pragma unroll
    for (int k = 0; k < 4; ++k) { int t = tid + 256 * k; if (t < n) sum += expf(sc[t] - mx); }
    red[tid] = sum; __syncthreads();
    for (int off = 128; off; off >>= 1) { if (tid < off) red[tid] += red[tid + off]; __syncthreads(); }
    float inv = 1.0f / red[0];
#pragma unroll
    for (int k = 0; k < 4; ++k) {
        int t = tid + 256 * k;
        sc[t] = (t < n) ? expf(sc[t] - mx) * inv : 0.0f;
    }
}

// ---- K4: A[b,s12,d] += sum_t attn[s12,t]*wte[idx[b,t],d].
// 2-deep gather pipeline, 16 rows/block. grid (64 tc, 8 b) x 192.
__global__ __launch_bounds__(192) void k4_accA(const int* __restrict__ idx,
                                               const float* __restrict__ wte,
                                               float* __restrict__ ws) {
    const float4* __restrict__ wte4 = reinterpret_cast<const float4*>(wte);
    __shared__ float wl[16 * 12];
    const int tc = blockIdx.x, b = blockIdx.y, tid = threadIdx.x;
    if (tid < 192) {
        int tl = tid / 12, s12 = tid % 12;
        wl[tid] = ws[OFF_SC + s12 * S + tc * 16 + tl];
    }
    __syncthreads();
    const int* __restrict__ ib = idx + b * S + tc * 16;
    float4 v0 = wte4[(size_t)ib[0] * 192 + tid];
    float4 v1 = wte4[(size_t)ib[1] * 192 + tid];
    float4 acc[12] = {};
#pragma unroll
    for (int tl = 0; tl < 16; ++tl) {
        float4 nx = {0,0,0,0};
        if (tl + 2 < 16) nx = wte4[(size_t)ib[tl + 2] * 192 + tid];
        const float* w = &wl[tl * 12];
#pragma unroll
        for (int s12 = 0; s12 < 12; ++s12) {
            float wv_ = w[s12];
            acc[s12].x += wv_ * v0.x;
            acc[s12].y += wv_ * v0.y;
            acc[s12].z += wv_ * v0.z;
            acc[s12].w += wv_ * v0.w;
        }
        v0 = v1; v1 = nx;
    }
#pragma unroll
    for (int s12 = 0; s12 < 12; ++s12) {
        float* dst = &ws[OFF_A + (b * NS + s12) * D + 4 * tid];
        atomicAdd(dst + 0, acc[s12].x);
        atomicAdd(dst + 1, acc[s12].y);
        atomicAdd(dst + 2, acc[s12].z);
        atomicAdd(dst + 3, acc[s12].w);
    }
}

// ---- K5: yv = (A - e_mean)*wv*invn*w_lr; block 288 also: yo[b,d] = sb[d]. grid 289 x 256
__global__ __launch_bounds__(256) void k5_yv(const int* __restrict__ idx,
                                             const float* __restrict__ wte,
                                             const float* __restrict__ wv,
                                             const float* __restrict__ wlr,
                                             float* __restrict__ ws) {
    if (blockIdx.x < 288) {
        int i = blockIdx.x * 256 + threadIdx.x;                   // < 73728
        int b = i / HD, f = i % HD, s12 = f / D, d = f % D;
        float em = ws[OFF_EMEAN + d] * (1.0f / V);
        float A  = ws[OFF_A + (b * NS + s12) * D + d];
        float invn = 1.0f / (float)(SLO + s12 + 1);
        ws[OFF_YV + i] = (A - em) * wv[11 * D + d] * invn * wlr[11];
    } else {
        for (int d = threadIdx.x; d < D; d += 256) {
            float em = ws[OFF_EMEAN + d] * (1.0f / V);
            float s = 0.f;
#pragma unroll
            for (int b = 0; b < 8; ++b) {
                int row = idx[b * S + (S - 1)];
                s += wte[(size_t)row * D + d];
            }
            float sb = (s - 8.0f * em) * (1.0f / (float)S);
#pragma unroll
            for (int b = 0; b < 8; ++b) ws[OFF_YO + b * D + d] = sb;
        }
    }
}

// ---- K6: yo[b,r] += sum_f yv[b,f]*w_o[r,f].  Wave per (row, k-quarter):
// 3072 waves, grid 768 x 256 -> ~12 blocks/CU queued, 4x waves vs R4.
__global__ __launch_bounds__(256) void k6_wo(const float* __restrict__ w_o,
                                             float* __restrict__ ws) {
    const int lane = threadIdx.x & 63;
    const int wid = (blockIdx.x * 256 + threadIdx.x) >> 6;    // 0..3071
    const int r = wid >> 2;                                   // 0..767
    const int kbase = (wid & 3) * 2304;
    float acc[8] = {0};
#pragma unroll
    for (int i = 0; i < 9; ++i) {
        int k = kbase + 4 * lane + 256 * i;
        float4 a0 = *reinterpret_cast<const float4*>(w_o + (size_t)r * HD + k);
#pragma unroll
        for (int b = 0; b < 8; ++b) {
            float4 y = *reinterpret_cast<const float4*>(ws + OFF_YV + b * HD + k);
            acc[b] += a0.x * y.x + a0.y * y.y + a0.z * y.z + a0.w * y.w;
        }
    }
    float z = fold8(acc, lane);
    if (lane < 8) atomicAdd(&ws[OFF_YO + lane * D + r], z);
}

// ---- K7: g[b,f] = gelu(sum_d yo[b,d]*w1[f,d]).  wave per f. grid 768 x 256
__global__ __launch_bounds__(256) void k7_mlp1(const float* __restrict__ w1,
                                               float* __restrict__ ws) {
    const int lane = threadIdx.x & 63;
    const int f = (blockIdx.x * 256 + threadIdx.x) >> 6;      // 0..3071
    float acc[8] = {0};
#pragma unroll
    for (int i = 0; i < 3; ++i) {
        int dcol = 4 * lane + 256 * i;
        float4 w = *reinterpret_cast<const float4*>(w1 + (size_t)f * D + dcol);
#pragma unroll
        for (int b = 0; b < 8; ++b) {
            float4 y = *reinterpret_cast<const float4*>(ws + OFF_YO + b * D + dcol);
            acc[b] += w.x * y.x + w.y * y.y + w.z * y.z + w.w * y.w;
        }
    }
    float z = fold8(acc, lane);
    if (lane < 8) {
        float g = 0.5f * z * (1.0f + erff(z * 0.70710678118654752f));
        ws[OFF_G + lane * DFF + f] = g;
    }
}

// ---- K8: x[b,d] = yo[b,d] + sum_f g[b,f]*w2[d,f].  Wave per (d, f-quarter):
// 3072 waves, grid 768 x 256. Atomic into zero-inited OFF_X; kc==0 adds yo.
__global__ __launch_bounds__(256) void k8_mlp2(const float* __restrict__ w2,
                                               float* __restrict__ ws) {
    const int lane = threadIdx.x & 63;
    const int wid = (blockIdx.x * 256 + threadIdx.x) >> 6;    // 0..3071
    const int dd = wid >> 2;                                  // 0..767
    const int kc = wid & 3;
    const int fbase = kc * 768;
    float acc[8] = {0};
#pragma unroll
    for (int i = 0; i < 3; ++i) {
        int fcol = fbase + 4 * lane + 256 * i;
        float4 w = *reinterpret_cast<const float4*>(w2 + (size_t)dd * DFF + fcol);
#pragma unroll
        for (int b = 0; b < 8; ++b) {
            float4 g = *reinterpret_cast<const float4*>(ws + OFF_G + b * DFF + fcol);
            acc[b] += w.x * g.x + w.y * g.y + w.z * g.z + w.w * g.w;
        }
    }
    float z = fold8(acc, lane);
    if (lane < 8) {
        if (kc == 0) z += ws[OFF_YO + lane * D + dd];
        atomicAdd(&ws[OFF_X + lane * D + dd], z);
    }
}

// ---- K9: logits[b,j] = x[b,:] . wte[j,:].  Block owns 64 consecutive rows;
// wave w handles rows base+w+4i. 2-row-deep prefetch (6 loads in flight).
__global__ __launch_bounds__(256) void k9_logits(const float* __restrict__ wte,
                                                 const float* __restrict__ ws,
                                                 float* __restrict__ out) {
    const int lane = threadIdx.x & 63;
    const int w = threadIdx.x >> 6;                           // 0..3
    float4 xr[8][3];
#pragma unroll
    for (int b = 0; b < 8; ++b)
#pragma unroll
        for (int i = 0; i < 3; ++i)
            xr[b][i] = *reinterpret_cast<const float4*>(ws + OFF_X + b * D + 4 * lane + 256 * i);
    int j = blockIdx.x * 64 + w;
    float4 c0[3], c1[3];
    if (j < V) {
#pragma unroll
        for (int i = 0; i < 3; ++i)
            c0[i] = *reinterpret_cast<const float4*>(wte + (size_t)j * D + 4 * lane + 256 * i);
    }
    if (j + 4 < V) {
#pragma unroll
        for (int i = 0; i < 3; ++i)
            c1[i] = *reinterpret_cast<const float4*>(wte + (size_t)(j + 4) * D + 4 * lane + 256 * i);
    }
#pragma unroll
    for (int it = 0; it < 16; ++it) {
        int jn = j + 8;
        float4 nw[3];
        if (it + 2 < 16 && jn < V) {
#pragma unroll
            for (int i = 0; i < 3; ++i)
                nw[i] = *reinterpret_cast<const float4*>(wte + (size_t)jn * D + 4 * lane + 256 * i);
        }
        if (j < V) {
            float acc[8];
#pragma unroll
            for (int b = 0; b < 8; ++b) {
                float a = 0.f;
#pragma unroll
                for (int i = 0; i < 3; ++i)
                    a += c0[i].x * xr[b][i].x + c0[i].y * xr[b][i].y +
                         c0[i].z * xr[b][i].z + c0[i].w * xr[b][i].w;
                acc[b] = a;
            }
            float z = fold8(acc, lane);
            if (lane < 8) out[(size_t)lane * V + j] = z;
        }
#pragma unroll
        for (int i = 0; i < 3; ++i) { c0[i] = c1[i]; c1[i] = nw[i]; }
        j += 4;
    }
}

extern "C" void kernel_launch(void* const* d_in, const int* in_sizes, int n_in,
                              void* d_out, int out_size, void* d_ws, size_t ws_size,
                              hipStream_t stream) {
    const int*   idx = (const int*)  d_in[0];
    const float* wte = (const float*)d_in[1];
    const float* wpe = (const float*)d_in[2];
    const float* wq  = (const float*)d_in[3];
    const float* wk  = (const float*)d_in[4];
    const float* wv  = (const float*)d_in[5];
    const float* wlr = (const float*)d_in[6];
    const float* w_o = (const float*)d_in[7];
    const float* w1  = (const float*)d_in[8];
    const float* w2  = (const float*)d_in[9];
    float* out = (float*)d_out;
    float* ws  = (float*)d_ws;

    // zero the atomic-accumulated regions: [e_mean + A] and [X]
    hipMemsetAsync(ws, 0, (size_t)(768 + B * NS * D) * sizeof(float), stream);
    hipMemsetAsync(ws + OFF_X, 0, (size_t)(B * D) * sizeof(float), stream);

    k1_emean <<<K1_G,         192, 0, stream>>>(wte, ws);
    k2_scores<<<256,          256, 0, stream>>>(wpe, wq, wk, ws);
    k3_softmax<<<12,          256, 0, stream>>>(ws);
    k4_accA  <<<dim3(64, 8),  192, 0, stream>>>(idx, wte, ws);
    k5_yv    <<<289,          256, 0, stream>>>(idx, wte, wv, wlr, ws);
    k6_wo    <<<768,          256, 0, stream>>>(w_o, ws);
    k7_mlp1  <<<768,          256, 0, stream>>>(w1, ws);
    k8_mlp2  <<<768,          256, 0, stream>>>(w2, ws);
    k9_logits<<<786,          256, 0, stream>>>(wte, ws, out);
}

// Round 6
// 464.980 us; speedup vs baseline: 1.3728x; 1.3728x over previous
//
#include <hip/hip_runtime.h>
#include <math.h>

#define B 8
#define S 1024
#define D 768
#define H 12
#define V 50257
#define DFF 3072
#define HD (H*D)      // 9216
#define SLO 1012      // first s needed (head 11, last 12 positions of y feed x row 1023)
#define NS 12

// workspace layout (float offsets)
#define OFF_EMEAN 0                     // 768   (atomic sum; divide by V on read)
#define OFF_A     768                   // B*NS*D = 73728 (atomic)
#define OFF_SC    (OFF_A + B*NS*D)      // NS*S = 12288 (scores -> attn in place)
#define OFF_YV    (OFF_SC + NS*S)       // B*HD = 73728
#define OFF_YO    (OFF_YV + B*HD)       // B*D = 6144
#define OFF_G     (OFF_YO + B*D)        // B*DFF = 24576
#define OFF_X     (OFF_G + B*DFF)       // B*D = 6144 (atomic; zeroed by memset2)

// ---- async global->LDS DMA (16B per lane per issue), explicit vmcnt gating.
// dest must be wave-uniform base; HW writes base + lane*16.
__device__ __forceinline__ void dma16(const float4* g, float4* l) {
    __builtin_amdgcn_global_load_lds(
        (__attribute__((address_space(1))) void*)g,
        (__attribute__((address_space(3))) void*)l, 16, 0, 0);
}
// wait until <= n vector-memory ops outstanding (gfx9 enc: vm[3:0], exp=7, lgkm=15)
#define WAITVM(n) __builtin_amdgcn_s_waitcnt(0xF70 | (n))

// ---- multi-value butterfly reductions ----------------------------------
__device__ __forceinline__ float fold8(const float acc[8], int lane) {
    float x[4];
#pragma unroll
    for (int i = 0; i < 4; ++i) {
        bool s = lane & 1;
        float a = s ? acc[2*i+1] : acc[2*i];
        float b = s ? acc[2*i]   : acc[2*i+1];
        x[i] = a + __shfl_xor(b, 1, 64);
    }
    float y[2];
#pragma unroll
    for (int i = 0; i < 2; ++i) {
        bool s = lane & 2;
        float a = s ? x[2*i+1] : x[2*i];
        float b = s ? x[2*i]   : x[2*i+1];
        y[i] = a + __shfl_xor(b, 2, 64);
    }
    bool s = lane & 4;
    float a = s ? y[1] : y[0];
    float b = s ? y[0] : y[1];
    float z = a + __shfl_xor(b, 4, 64);
    z += __shfl_xor(z, 8, 64);
    z += __shfl_xor(z, 16, 64);
    z += __shfl_xor(z, 32, 64);
    return z;
}

__device__ __forceinline__ float fold16(const float acc[16], int lane) {
    float x[8];
#pragma unroll
    for (int i = 0; i < 8; ++i) {
        bool s = lane & 1;
        float a = s ? acc[2*i+1] : acc[2*i];
        float b = s ? acc[2*i]   : acc[2*i+1];
        x[i] = a + __shfl_xor(b, 1, 64);
    }
    float y[4];
#pragma unroll
    for (int i = 0; i < 4; ++i) {
        bool s = lane & 2;
        float a = s ? x[2*i+1] : x[2*i];
        float b = s ? x[2*i]   : x[2*i+1];
        y[i] = a + __shfl_xor(b, 2, 64);
    }
    float z2[2];
#pragma unroll
    for (int i = 0; i < 2; ++i) {
        bool s = lane & 4;
        float a = s ? y[2*i+1] : y[2*i];
        float b = s ? y[2*i]   : y[2*i+1];
        z2[i] = a + __shfl_xor(b, 4, 64);
    }
    bool s = lane & 8;
    float a = s ? z2[1] : z2[0];
    float b = s ? z2[0] : z2[1];
    float z = a + __shfl_xor(b, 8, 64);
    z += __shfl_xor(z, 16, 64);
    z += __shfl_xor(z, 32, 64);
    return z;
}

// ---- K1: column sums of wte via LDS-DMA pipeline. grid 512 x 192.
// Block owns ~98 contiguous rows. Wave w streams its 1KB third of each row
// through an 8-slot LDS ring; 8 DMAs in flight/wave (no VGPR staging).
#define K1_BLK 512
__global__ __launch_bounds__(192) void k1_emean(const float* __restrict__ wte,
                                                float* __restrict__ ws) {
    const float4* __restrict__ wte4 = reinterpret_cast<const float4*>(wte);
    __shared__ float4 stage[8 * 192];                     // 24 KB ring
    const int tid = threadIdx.x, w = tid >> 6, lane = tid & 63;
    const int b = blockIdx.x;
    const int q = V / K1_BLK;                             // 98
    const int rem = V - q * K1_BLK;                       // 81
    const int r0 = b * q + (b < rem ? b : rem);
    const int nr = q + (b < rem ? 1 : 0);                 // 98 or 99 (>= 8)
    const float4* gsrc = wte4 + (size_t)r0 * 192 + w * 64 + lane;
#pragma unroll
    for (int s = 0; s < 8; ++s)
        dma16(gsrc + (size_t)s * 192, &stage[s * 192 + w * 64]);
    float4 a = {0, 0, 0, 0};
    int r = 0;
    for (; r < nr - 8; ++r) {
        WAITVM(7);                                        // oldest row landed
        float4 t = stage[(r & 7) * 192 + tid];
        a.x += t.x; a.y += t.y; a.z += t.z; a.w += t.w;
        dma16(gsrc + (size_t)(r + 8) * 192, &stage[(r & 7) * 192 + w * 64]);
    }
    WAITVM(0);
    for (; r < nr; ++r) {
        float4 t = stage[(r & 7) * 192 + tid];
        a.x += t.x; a.y += t.y; a.z += t.z; a.w += t.w;
    }
    atomicAdd(&ws[OFF_EMEAN + 4 * tid + 0], a.x);
    atomicAdd(&ws[OFF_EMEAN + 4 * tid + 1], a.y);
    atomicAdd(&ws[OFF_EMEAN + 4 * tid + 2], a.z);
    atomicAdd(&ws[OFF_EMEAN + 4 * tid + 3], a.w);
}

// ---- K2: scores[s12,t] = sum_d wpe[t,d]*wpe[s+1,d]*wq[11,d]*wk[11,d].
// wave per t. grid 256 x 256
__global__ __launch_bounds__(256) void k2_scores(const float* __restrict__ wpe,
                                                 const float* __restrict__ wq,
                                                 const float* __restrict__ wk,
                                                 float* __restrict__ ws) {
    const float4* __restrict__ wpe4 = reinterpret_cast<const float4*>(wpe);
    const int lane = threadIdx.x & 63;
    const int t = (blockIdx.x * 256 + threadIdx.x) >> 6;      // 0..1023
    float4 p[3], qk[3];
#pragma unroll
    for (int i = 0; i < 3; ++i) {
        p[i] = wpe4[(size_t)t * 192 + lane + 64 * i];
        float4 q = *reinterpret_cast<const float4*>(wq + 11 * D + 4 * lane + 256 * i);
        float4 k = *reinterpret_cast<const float4*>(wk + 11 * D + 4 * lane + 256 * i);
        qk[i].x = p[i].x * q.x * k.x;
        qk[i].y = p[i].y * q.y * k.y;
        qk[i].z = p[i].z * q.z * k.z;
        qk[i].w = p[i].w * q.w * k.w;
    }
    float acc[16];
#pragma unroll
    for (int s12 = 0; s12 < 12; ++s12) {
        float a = 0.f;
#pragma unroll
        for (int i = 0; i < 3; ++i) {
            float4 pe = wpe4[(size_t)(SLO + s12 + 1) * 192 + lane + 64 * i];
            a += pe.x * qk[i].x + pe.y * qk[i].y + pe.z * qk[i].z + pe.w * qk[i].w;
        }
        acc[s12] = a;
    }
    acc[12] = acc[13] = acc[14] = acc[15] = 0.f;
    float z = fold16(acc, lane);
    if (lane < 12) ws[OFF_SC + lane * S + t] = z;
}

// ---- K3: softmax rows (masked t<=s), writes attn in place. grid 12 x 256
__global__ __launch_bounds__(256) void k3_softmax(float* __restrict__ ws) {
    __shared__ float red[256];
    const int s12 = blockIdx.x, tid = threadIdx.x;
    const int n = SLO + s12 + 1;
    float* sc = ws + OFF_SC + s12 * S;
    float m = -1e30f;
#pragma unroll
    for (int k = 0; k < 4; ++k) { int t = tid + 256 * k; if (t < n) m = fmaxf(m, sc[t]); }
    red[tid] = m; __syncthreads();
    for (int off = 128; off; off >>= 1) { if (tid < off) red[tid] = fmaxf(red[tid], red[tid + off]); __syncthreads(); }
    float mx = red[0]; __syncthreads();
    float sum = 0.f;
#pragma unroll
    for (int k = 0; k < 4; ++k) { int t = tid + 256 * k; if (t < n) sum += expf(sc[t] - mx); }
    red[tid] = sum; __syncthreads();
    for (int off = 128; off; off >>= 1) { if (tid < off) red[tid] += red[tid + off]; __syncthreads(); }
    float inv = 1.0f / red[0];
#pragma unroll
    for (int k = 0; k < 4; ++k) {
        int t = tid + 256 * k;
        sc[t] = (t < n) ? expf(sc[t] - mx) * inv : 0.0f;
    }
}

// ---- K4: A[b,s12,d] += sum_t attn[s12,t]*wte[idx[b,t],d].
// 2-deep gather pipeline, 16 rows/block. grid (64 tc, 8 b) x 192.
__global__ __launch_bounds__(192) void k4_accA(const int* __restrict__ idx,
                                               const float* __restrict__ wte,
                                               float* __restrict__ ws) {
    const float4* __restrict__ wte4 = reinterpret_cast<const float4*>(wte);
    __shared__ float wl[16 * 12];
    const int tc = blockIdx.x, b = blockIdx.y, tid = threadIdx.x;
    if (tid < 192) {
        int tl = tid / 12, s12 = tid % 12;
        wl[tid] = ws[OFF_SC + s12 * S + tc * 16 + tl];
    }
    __syncthreads();
    const int* __restrict__ ib = idx + b * S + tc * 16;
    float4 v0 = wte4[(size_t)ib[0] * 192 + tid];
    float4 v1 = wte4[(size_t)ib[1] * 192 + tid];
    float4 acc[12] = {};
#pragma unroll
    for (int tl = 0; tl < 16; ++tl) {
        float4 nx = {0,0,0,0};
        if (tl + 2 < 16) nx = wte4[(size_t)ib[tl + 2] * 192 + tid];
        const float* w = &wl[tl * 12];
#pragma unroll
        for (int s12 = 0; s12 < 12; ++s12) {
            float wv_ = w[s12];
            acc[s12].x += wv_ * v0.x;
            acc[s12].y += wv_ * v0.y;
            acc[s12].z += wv_ * v0.z;
            acc[s12].w += wv_ * v0.w;
        }
        v0 = v1; v1 = nx;
    }
#pragma unroll
    for (int s12 = 0; s12 < 12; ++s12) {
        float* dst = &ws[OFF_A + (b * NS + s12) * D + 4 * tid];
        atomicAdd(dst + 0, acc[s12].x);
        atomicAdd(dst + 1, acc[s12].y);
        atomicAdd(dst + 2, acc[s12].z);
        atomicAdd(dst + 3, acc[s12].w);
    }
}

// ---- K5: yv = (A - e_mean)*wv*invn*w_lr; block 288 also: yo[b,d] = sb[d]. grid 289 x 256
__global__ __launch_bounds__(256) void k5_yv(const int* __restrict__ idx,
                                             const float* __restrict__ wte,
                                             const float* __restrict__ wv,
                                             const float* __restrict__ wlr,
                                             float* __restrict__ ws) {
    if (blockIdx.x < 288) {
        int i = blockIdx.x * 256 + threadIdx.x;                   // < 73728
        int b = i / HD, f = i % HD, s12 = f / D, d = f % D;
        float em = ws[OFF_EMEAN + d] * (1.0f / V);
        float A  = ws[OFF_A + (b * NS + s12) * D + d];
        float invn = 1.0f / (float)(SLO + s12 + 1);
        ws[OFF_YV + i] = (A - em) * wv[11 * D + d] * invn * wlr[11];
    } else {
        for (int d = threadIdx.x; d < D; d += 256) {
            float em = ws[OFF_EMEAN + d] * (1.0f / V);
            float s = 0.f;
#pragma unroll
            for (int b = 0; b < 8; ++b) {
                int row = idx[b * S + (S - 1)];
                s += wte[(size_t)row * D + d];
            }
            float sb = (s - 8.0f * em) * (1.0f / (float)S);
#pragma unroll
            for (int b = 0; b < 8; ++b) ws[OFF_YO + b * D + d] = sb;
        }
    }
}

// ---- K6: yo[b,r] += sum_f yv[b,f]*w_o[r,f].  Wave per (row, k-quarter). grid 768 x 256
__global__ __launch_bounds__(256) void k6_wo(const float* __restrict__ w_o,
                                             float* __restrict__ ws) {
    const int lane = threadIdx.x & 63;
    const int wid = (blockIdx.x * 256 + threadIdx.x) >> 6;    // 0..3071
    const int r = wid >> 2;                                   // 0..767
    const int kbase = (wid & 3) * 2304;
    float acc[8] = {0};
#pragma unroll
    for (int i = 0; i < 9; ++i) {
        int k = kbase + 4 * lane + 256 * i;
        float4 a0 = *reinterpret_cast<const float4*>(w_o + (size_t)r * HD + k);
#pragma unroll
        for (int b = 0; b < 8; ++b) {
            float4 y = *reinterpret_cast<const float4*>(ws + OFF_YV + b * HD + k);
            acc[b] += a0.x * y.x + a0.y * y.y + a0.z * y.z + a0.w * y.w;
        }
    }
    float z = fold8(acc, lane);
    if (lane < 8) atomicAdd(&ws[OFF_YO + lane * D + r], z);
}

// ---- K7: g[b,f] = gelu(sum_d yo[b,d]*w1[f,d]).  wave per f. grid 768 x 256
__global__ __launch_bounds__(256) void k7_mlp1(const float* __restrict__ w1,
                                               float* __restrict__ ws) {
    const int lane = threadIdx.x & 63;
    const int f = (blockIdx.x * 256 + threadIdx.x) >> 6;      // 0..3071
    float acc[8] = {0};
#pragma unroll
    for (int i = 0; i < 3; ++i) {
        int dcol = 4 * lane + 256 * i;
        float4 w = *reinterpret_cast<const float4*>(w1 + (size_t)f * D + dcol);
#pragma unroll
        for (int b = 0; b < 8; ++b) {
            float4 y = *reinterpret_cast<const float4*>(ws + OFF_YO + b * D + dcol);
            acc[b] += w.x * y.x + w.y * y.y + w.z * y.z + w.w * y.w;
        }
    }
    float z = fold8(acc, lane);
    if (lane < 8) {
        float g = 0.5f * z * (1.0f + erff(z * 0.70710678118654752f));
        ws[OFF_G + lane * DFF + f] = g;
    }
}

// ---- K8: x[b,d] = yo[b,d] + sum_f g[b,f]*w2[d,f].  Wave per (d, f-quarter). grid 768 x 256
__global__ __launch_bounds__(256) void k8_mlp2(const float* __restrict__ w2,
                                               float* __restrict__ ws) {
    const int lane = threadIdx.x & 63;
    const int wid = (blockIdx.x * 256 + threadIdx.x) >> 6;    // 0..3071
    const int dd = wid >> 2;                                  // 0..767
    const int kc = wid & 3;
    const int fbase = kc * 768;
    float acc[8] = {0};
#pragma unroll
    for (int i = 0; i < 3; ++i) {
        int fcol = fbase + 4 * lane + 256 * i;
        float4 w = *reinterpret_cast<const float4*>(w2 + (size_t)dd * DFF + fcol);
#pragma unroll
        for (int b = 0; b < 8; ++b) {
            float4 g = *reinterpret_cast<const float4*>(ws + OFF_G + b * DFF + fcol);
            acc[b] += w.x * g.x + w.y * g.y + w.z * g.z + w.w * g.w;
        }
    }
    float z = fold8(acc, lane);
    if (lane < 8) {
        if (kc == 0) z += ws[OFF_YO + lane * D + dd];
        atomicAdd(&ws[OFF_X + lane * D + dd], z);
    }
}

// ---- K9: logits[b,j] = x[b,:] . wte[j,:] via LDS-DMA row pipeline.
// grid 512 x 256; each wave owns ~24 contiguous rows, streams them through
// a private 4-slot x 3KB LDS ring (12 DMAs in flight), x held in registers.
__global__ __launch_bounds__(256) void k9_logits(const float* __restrict__ wte,
                                                 const float* __restrict__ ws,
                                                 float* __restrict__ out) {
    const float4* __restrict__ wte4 = reinterpret_cast<const float4*>(wte);
    __shared__ float4 stage[4][4 * 192];                  // 4 waves x 12 KB
    const int tid = threadIdx.x, w = tid >> 6, lane = tid & 63;
    float4 xr[8][3];
#pragma unroll
    for (int b = 0; b < 8; ++b)
#pragma unroll
        for (int i = 0; i < 3; ++i)
            xr[b][i] = *reinterpret_cast<const float4*>(ws + OFF_X + b * D + 4 * lane + 256 * i);
    const int gw = blockIdx.x * 4 + w;                    // 0..2047
    const int q = V / 2048;                               // 24
    const int rem = V - q * 2048;                         // 1105
    const int r0 = gw * q + (gw < rem ? gw : rem);
    const int nr = q + (gw < rem ? 1 : 0);                // 24 or 25 (>= 4)
    const float4* gsrc = wte4 + (size_t)r0 * 192 + lane;
    float4* st = stage[w];
#pragma unroll
    for (int s = 0; s < 4; ++s)
#pragma unroll
        for (int i = 0; i < 3; ++i)
            dma16(gsrc + (size_t)s * 192 + i * 64, &st[s * 192 + i * 64]);
    int r = 0;
    for (; r < nr - 4; ++r) {
        WAITVM(9);                                        // oldest row's 3 segs landed
        const int sl = (r & 3) * 192;
        float4 c0 = st[sl + lane];
        float4 c1 = st[sl + 64 + lane];
        float4 c2 = st[sl + 128 + lane];
        float acc[8];
#pragma unroll
        for (int b = 0; b < 8; ++b) {
            acc[b] = c0.x * xr[b][0].x + c0.y * xr[b][0].y + c0.z * xr[b][0].z + c0.w * xr[b][0].w
                   + c1.x * xr[b][1].x + c1.y * xr[b][1].y + c1.z * xr[b][1].z + c1.w * xr[b][1].w
                   + c2.x * xr[b][2].x + c2.y * xr[b][2].y + c2.z * xr[b][2].z + c2.w * xr[b][2].w;
        }
        float z = fold8(acc, lane);
        if (lane < 8) out[(size_t)lane * V + (r0 + r)] = z;
#pragma unroll
        for (int i = 0; i < 3; ++i)
            dma16(gsrc + (size_t)(r + 4) * 192 + i * 64, &st[sl + i * 64]);
    }
    WAITVM(0);
    for (; r < nr; ++r) {
        const int sl = (r & 3) * 192;
        float4 c0 = st[sl + lane];
        float4 c1 = st[sl + 64 + lane];
        float4 c2 = st[sl + 128 + lane];
        float acc[8];
#pragma unroll
        for (int b = 0; b < 8; ++b) {
            acc[b] = c0.x * xr[b][0].x + c0.y * xr[b][0].y + c0.z * xr[b][0].z + c0.w * xr[b][0].w
                   + c1.x * xr[b][1].x + c1.y * xr[b][1].y + c1.z * xr[b][1].z + c1.w * xr[b][1].w
                   + c2.x * xr[b][2].x + c2.y * xr[b][2].y + c2.z * xr[b][2].z + c2.w * xr[b][2].w;
        }
        float z = fold8(acc, lane);
        if (lane < 8) out[(size_t)lane * V + (r0 + r)] = z;
    }
}

extern "C" void kernel_launch(void* const* d_in, const int* in_sizes, int n_in,
                              void* d_out, int out_size, void* d_ws, size_t ws_size,
                              hipStream_t stream) {
    const int*   idx = (const int*)  d_in[0];
    const float* wte = (const float*)d_in[1];
    const float* wpe = (const float*)d_in[2];
    const float* wq  = (const float*)d_in[3];
    const float* wk  = (const float*)d_in[4];
    const float* wv  = (const float*)d_in[5];
    const float* wlr = (const float*)d_in[6];
    const float* w_o = (const float*)d_in[7];
    const float* w1  = (const float*)d_in[8];
    const float* w2  = (const float*)d_in[9];
    float* out = (float*)d_out;
    float* ws  = (float*)d_ws;

    // zero the atomic-accumulated regions: [e_mean + A] and [X]
    hipMemsetAsync(ws, 0, (size_t)(768 + B * NS * D) * sizeof(float), stream);
    hipMemsetAsync(ws + OFF_X, 0, (size_t)(B * D) * sizeof(float), stream);

    k1_emean <<<K1_BLK,       192, 0, stream>>>(wte, ws);
    k2_scores<<<256,          256, 0, stream>>>(wpe, wq, wk, ws);
    k3_softmax<<<12,          256, 0, stream>>>(ws);
    k4_accA  <<<dim3(64, 8),  192, 0, stream>>>(idx, wte, ws);
    k5_yv    <<<289,          256, 0, stream>>>(idx, wte, wv, wlr, ws);
    k6_wo    <<<768,          256, 0, stream>>>(w_o, ws);
    k7_mlp1  <<<768,          256, 0, stream>>>(w1, ws);
    k8_mlp2  <<<768,          256, 0, stream>>>(w2, ws);
    k9_logits<<<512,          256, 0, stream>>>(wte, ws, out);
}